// Round 3
// baseline (566.324 us; speedup 1.0000x reference)
//
#include <hip/hip_runtime.h>
#include <hip/hip_bf16.h>

// GAT forward: N=8192, IN=512, HID=256, OUT=64.
// exp-factorization + monotonicity: w_ij = A_ij * max( e^{s1_i} e^{s2_j},
//                                                      e^{0.2 s1_i} e^{0.2 s2_j} )
// k_attn v3: barrier-free, LDS-free streaming MFMA. All operands pre-laid-out in
// MFMA-fragment-contiguous form: idx(n,k) = ((n>>4)*(K/8) + (k>>3))*128 + (n&15)*8 + (k&7)
// so every wave load is 1 KB contiguous. A-tile deduped across the 4 waves via L1.

typedef float f32x4 __attribute__((ext_vector_type(4)));
typedef short s16x8 __attribute__((ext_vector_type(8)));

#define NN 8192
#define INDIM 512
#define HIDD 256
#define OUTD 64

static __device__ __forceinline__ short f2bf(float x) {
    __hip_bfloat16 h = __float2bfloat16(x);
    return __builtin_bit_cast(short, h);
}

static __device__ __forceinline__ void split_bf(float x, short& hi, short& lo) {
    short h = f2bf(x);
    unsigned int hb = ((unsigned int)(unsigned short)h) << 16;
    float hf = __builtin_bit_cast(float, hb);
    hi = h;
    lo = f2bf(x - hf);
}

// ---- prep: X (f32 [8192][512]) -> bf16-hi in A-frag-contiguous layout ---------------
__global__ void k_prepX(const float* __restrict__ X, short* __restrict__ XBhi) {
    int t = blockIdx.x * 256 + threadIdx.x;        // 4,194,304
    int r = t >> 9, k = t & 511;
    XBhi[(r >> 4) * 8192 + (k >> 3) * 128 + (r & 15) * 8 + (k & 7)] = f2bf(X[t]);
}

// ---- prep: W1 (f32 [512][256]) -> split hi/lo bf16 in B-frag-contiguous layout ------
__global__ void k_prepW(const float* __restrict__ W1,
                        short* __restrict__ WBhi, short* __restrict__ WBlo) {
    int t = blockIdx.x * 256 + threadIdx.x;        // 131,072
    int k = t >> 8, n = t & 255;                   // W1[k][n] read coalesced
    short h, l; split_bf(W1[t], h, l);
    int idx = (n >> 4) * 8192 + (k >> 3) * 128 + (n & 15) * 8 + (k & 7);
    WBhi[idx] = h;
    WBlo[idx] = l;
}

// ---- k_h1: H1 = X@W1 + b1 (Xhi x (Whi+Wlo), 2 MFMA) ---------------------------------
// Grid 512 (16 rows/block), 4 waves = 4 hid-groups of 64. All loads 1KB-contiguous.
// Writes H1TB (bf16, frag-contiguous over (hid, j=row)) + per-node exp factors.
__global__ void __launch_bounds__(256, 2)
k_h1(const short* __restrict__ XBhi, const short* __restrict__ WBhi,
     const short* __restrict__ WBlo, const float* __restrict__ b1,
     const float* __restrict__ avec, unsigned short* __restrict__ H1TB,
     float* __restrict__ alw, float* __restrict__ bew, float* __restrict__ uvw) {
    __shared__ float s1p[4][16];
    __shared__ float s2p[4][16];
    const int tid = threadIdx.x;
    const int wn = tid >> 6, lane = tid & 63;
    const int q = lane >> 4, m16 = lane & 15;
    const int blk = blockIdx.x;

    f32x4 zero4 = {0.f, 0.f, 0.f, 0.f};
    f32x4 acc[4];
#pragma unroll
    for (int nt = 0; nt < 4; ++nt) acc[nt] = zero4;

    const short* xh = XBhi + blk * 8192 + q * 128 + m16 * 8;
    const short* wh = WBhi + wn * 4 * 8192 + q * 128 + m16 * 8;
    const short* wl = WBlo + wn * 4 * 8192 + q * 128 + m16 * 8;

    for (int c = 0; c < 16; ++c) {                 // k-chunk of 32
        s16x8 ahi = *(const s16x8*)(xh + c * 512);
#pragma unroll
        for (int nt = 0; nt < 4; ++nt) {
            s16x8 bhi = *(const s16x8*)(wh + nt * 8192 + c * 512);
            s16x8 blo = *(const s16x8*)(wl + nt * 8192 + c * 512);
            acc[nt] = __builtin_amdgcn_mfma_f32_16x16x32_bf16(ahi, bhi, acc[nt], 0, 0, 0);
            acc[nt] = __builtin_amdgcn_mfma_f32_16x16x32_bf16(ahi, blo, acc[nt], 0, 0, 0);
        }
    }

    float p1[4] = {0.f, 0.f, 0.f, 0.f};
    float p2[4] = {0.f, 0.f, 0.f, 0.f};
#pragma unroll
    for (int nt = 0; nt < 4; ++nt) {
        const int col = wn * 64 + nt * 16 + m16;
        const float b1v = b1[col];
        const float a1v = avec[col];
        const float a2v = avec[HIDD + col];
        float v0 = acc[nt][0] + b1v;
        float v1 = acc[nt][1] + b1v;
        float v2 = acc[nt][2] + b1v;
        float v3 = acc[nt][3] + b1v;
        ushort4 us;
        us.x = (unsigned short)f2bf(v0);
        us.y = (unsigned short)f2bf(v1);
        us.z = (unsigned short)f2bf(v2);
        us.w = (unsigned short)f2bf(v3);
        // H1TB idx(hid=col, j=row): rows blk*16 + q*4 + r
        const int idx = ((wn * 4 + nt) * 1024 + blk * 2 + (q >> 1)) * 128
                        + m16 * 8 + (q & 1) * 4;
        *(ushort4*)(H1TB + idx) = us;
        p1[0] += v0 * a1v; p1[1] += v1 * a1v; p1[2] += v2 * a1v; p1[3] += v3 * a1v;
        p2[0] += v0 * a2v; p2[1] += v1 * a2v; p2[2] += v2 * a2v; p2[3] += v3 * a2v;
    }
#pragma unroll
    for (int off = 1; off < 16; off <<= 1) {
#pragma unroll
        for (int r = 0; r < 4; ++r) {
            p1[r] += __shfl_xor(p1[r], off);
            p2[r] += __shfl_xor(p2[r], off);
        }
    }
    if (m16 == 0) {
#pragma unroll
        for (int r = 0; r < 4; ++r) {
            s1p[wn][q * 4 + r] = p1[r];
            s2p[wn][q * 4 + r] = p2[r];
        }
    }
    __syncthreads();
    if (tid < 16) {
        const int i = blk * 16 + tid;
        float s1 = s1p[0][tid] + s1p[1][tid] + s1p[2][tid] + s1p[3][tid];
        float s2 = s2p[0][tid] + s2p[1][tid] + s2p[2][tid] + s2p[3][tid];
        alw[i] = expf(s1);
        bew[i] = expf(0.2f * s1);
        uvw[2 * i]     = expf(s2);
        uvw[2 * i + 1] = expf(0.2f * s2);
    }
}

// ---- k_attn: H2acc += W @ H1, Z += rowsum(W). Barrier-free streaming. ---------------
// Grid 2048 = mb(256, 32 rows) x ks(8, 1024 j). Block 256 = 4 waves, each wave:
// 32 rows (2 row-groups) x 64 hid (nt=4). A-tile identical across waves (L1 dedup).
__global__ void __launch_bounds__(256, 4)
k_attn(const int* __restrict__ A, const unsigned short* __restrict__ H1TB,
       const float* __restrict__ alw, const float* __restrict__ bew,
       const float* __restrict__ uvw,
       float* __restrict__ H2acc, float* __restrict__ Zw) {
    const int tid = threadIdx.x;
    const int wn = tid >> 6, lane = tid & 63;
    const int q = lane >> 4, m16 = lane & 15;
    const int ks = blockIdx.x & 7;                 // XCD-aligned K-slice
    const int mb = blockIdx.x >> 3;
    const int row0 = mb * 32 + m16, row1 = row0 + 16;
    const float al0 = alw[row0], be0 = bew[row0];
    const float al1 = alw[row1], be1 = bew[row1];
    const int j0 = ks * 1024;

    const int* Ap0 = A + (size_t)row0 * NN + j0 + q * 8;
    const int* Ap1 = A + (size_t)row1 * NN + j0 + q * 8;
    const float* uvp = uvw + 2 * (j0 + q * 8);
    const unsigned short* Hp = H1TB + ((size_t)(wn * 4) * 1024 + ks * 128 + q) * 128 + m16 * 8;

    f32x4 zero4 = {0.f, 0.f, 0.f, 0.f};
    f32x4 acc[8];                                  // [nt][rg]
#pragma unroll
    for (int i = 0; i < 8; ++i) acc[i] = zero4;
    float z0 = 0.f, z1 = 0.f;

    int4 a00 = *(const int4*)(Ap0);
    int4 a01 = *(const int4*)(Ap0 + 4);
    int4 a10 = *(const int4*)(Ap1);
    int4 a11 = *(const int4*)(Ap1 + 4);

    for (int t = 0; t < 32; ++t) {
        int4 n00, n01, n10, n11;
        if (t < 31) {                              // distance-1 A prefetch
            n00 = *(const int4*)(Ap0 + 32);
            n01 = *(const int4*)(Ap0 + 36);
            n10 = *(const int4*)(Ap1 + 32);
            n11 = *(const int4*)(Ap1 + 36);
        }
        float4 uv0 = *(const float4*)(uvp);
        float4 uv1 = *(const float4*)(uvp + 4);
        float4 uv2 = *(const float4*)(uvp + 8);
        float4 uv3 = *(const float4*)(uvp + 12);

        float w0[8], w1[8];
        w0[0] = (a00.x > 0) ? fmaxf(al0 * uv0.x, be0 * uv0.y) : 0.f;
        w0[1] = (a00.y > 0) ? fmaxf(al0 * uv0.z, be0 * uv0.w) : 0.f;
        w0[2] = (a00.z > 0) ? fmaxf(al0 * uv1.x, be0 * uv1.y) : 0.f;
        w0[3] = (a00.w > 0) ? fmaxf(al0 * uv1.z, be0 * uv1.w) : 0.f;
        w0[4] = (a01.x > 0) ? fmaxf(al0 * uv2.x, be0 * uv2.y) : 0.f;
        w0[5] = (a01.y > 0) ? fmaxf(al0 * uv2.z, be0 * uv2.w) : 0.f;
        w0[6] = (a01.z > 0) ? fmaxf(al0 * uv3.x, be0 * uv3.y) : 0.f;
        w0[7] = (a01.w > 0) ? fmaxf(al0 * uv3.z, be0 * uv3.w) : 0.f;
        w1[0] = (a10.x > 0) ? fmaxf(al1 * uv0.x, be1 * uv0.y) : 0.f;
        w1[1] = (a10.y > 0) ? fmaxf(al1 * uv0.z, be1 * uv0.w) : 0.f;
        w1[2] = (a10.z > 0) ? fmaxf(al1 * uv1.x, be1 * uv1.y) : 0.f;
        w1[3] = (a10.w > 0) ? fmaxf(al1 * uv1.z, be1 * uv1.w) : 0.f;
        w1[4] = (a11.x > 0) ? fmaxf(al1 * uv2.x, be1 * uv2.y) : 0.f;
        w1[5] = (a11.y > 0) ? fmaxf(al1 * uv2.z, be1 * uv2.w) : 0.f;
        w1[6] = (a11.z > 0) ? fmaxf(al1 * uv3.x, be1 * uv3.y) : 0.f;
        w1[7] = (a11.w > 0) ? fmaxf(al1 * uv3.z, be1 * uv3.w) : 0.f;
        z0 += (w0[0] + w0[1] + w0[2] + w0[3]) + (w0[4] + w0[5] + w0[6] + w0[7]);
        z1 += (w1[0] + w1[1] + w1[2] + w1[3]) + (w1[4] + w1[5] + w1[6] + w1[7]);

        s16x8 af0, af1;
#pragma unroll
        for (int j = 0; j < 8; ++j) { af0[j] = f2bf(w0[j]); af1[j] = f2bf(w1[j]); }

#pragma unroll
        for (int nt = 0; nt < 4; ++nt) {
            s16x8 bf = *(const s16x8*)(Hp + (size_t)nt * 131072 + t * 512);
            acc[nt * 2 + 0] = __builtin_amdgcn_mfma_f32_16x16x32_bf16(af0, bf, acc[nt * 2 + 0], 0, 0, 0);
            acc[nt * 2 + 1] = __builtin_amdgcn_mfma_f32_16x16x32_bf16(af1, bf, acc[nt * 2 + 1], 0, 0, 0);
        }
        if (t < 31) { a00 = n00; a01 = n01; a10 = n10; a11 = n11; }
        Ap0 += 32; Ap1 += 32; uvp += 64;
    }

    // Z row-sums: reduce over q (lane bits 4,5); wave 0 only (all waves compute same W).
    z0 += __shfl_xor(z0, 16); z0 += __shfl_xor(z0, 32);
    z1 += __shfl_xor(z1, 16); z1 += __shfl_xor(z1, 32);
    if (wn == 0 && q == 0) {
        atomicAdd(&Zw[row0], z0);
        atomicAdd(&Zw[row1], z1);
    }

#pragma unroll
    for (int nt = 0; nt < 4; ++nt) {
        const int col = wn * 64 + nt * 16 + m16;
#pragma unroll
        for (int rg = 0; rg < 2; ++rg) {
            const int rowb = mb * 32 + rg * 16 + q * 4;
#pragma unroll
            for (int r = 0; r < 4; ++r)
                atomicAdd(&H2acc[(size_t)(rowb + r) * HIDD + col], acc[nt * 2 + rg][r]);
        }
    }
}

// ---- k_out: out = sigmoid((H2acc/Z) @ Omega + beta), rows-inner (om read once) ------
__global__ void __launch_bounds__(256)
k_out(const float* __restrict__ H2acc, const float* __restrict__ Zw,
      const float* __restrict__ Omega, const float* __restrict__ beta,
      float* __restrict__ out) {
    __shared__ float om[HIDD * OUTD];  // 64 KB
    const int tid = threadIdx.x;
    for (int idx = tid; idx < HIDD * OUTD; idx += 256) om[idx] = Omega[idx];
    __syncthreads();
    const int wave = tid >> 6, o = tid & 63;
    const int i0 = blockIdx.x * 32 + wave * 8;
    float acc[8] = {0.f, 0.f, 0.f, 0.f, 0.f, 0.f, 0.f, 0.f};
    for (int c = 0; c < HIDD; c += 4) {
        const float o0 = om[(c + 0) * OUTD + o];
        const float o1 = om[(c + 1) * OUTD + o];
        const float o2 = om[(c + 2) * OUTD + o];
        const float o3 = om[(c + 3) * OUTD + o];
#pragma unroll
        for (int r = 0; r < 8; ++r) {
            float4 h = *(const float4*)(H2acc + (size_t)(i0 + r) * HIDD + c);  // uniform -> s_load
            acc[r] = fmaf(h.x, o0, fmaf(h.y, o1, fmaf(h.z, o2, fmaf(h.w, o3, acc[r]))));
        }
    }
    const float bv = beta[o];
#pragma unroll
    for (int r = 0; r < 8; ++r) {
        const float logit = acc[r] / Zw[i0 + r] + bv;
        out[(size_t)(i0 + r) * OUTD + o] = 1.0f / (1.0f + expf(-logit));
    }
}

extern "C" void kernel_launch(void* const* d_in, const int* in_sizes, int n_in,
                              void* d_out, int out_size, void* d_ws, size_t ws_size,
                              hipStream_t stream) {
    const float* X     = (const float*)d_in[0];
    const int*   A     = (const int*)d_in[1];
    const float* W1    = (const float*)d_in[2];
    const float* b1    = (const float*)d_in[3];
    const float* avec  = (const float*)d_in[4];
    const float* Omega = (const float*)d_in[5];
    const float* beta  = (const float*)d_in[6];
    float* out = (float*)d_out;

    char* ws = (char*)d_ws;
    unsigned short* H1TB = (unsigned short*)(ws + 0);       // 4,194,304
    // XBhi aliases the Zw/H2acc region: consumed by k_h1 BEFORE the memset.
    short* XBhi  = (short*)(ws + 4194304);                  // 8,388,608
    float* Zw    = (float*)(ws + 4194304);                  // 32,768   (after k_h1)
    float* H2acc = (float*)(ws + 4227072);                  // 8,388,608 (end 12,615,680)
    short* WBhi  = (short*)(ws + 12615680);                 // 262,144
    short* WBlo  = (short*)(ws + 12877824);                 // 262,144
    float* alw   = (float*)(ws + 13139968);                 // 32,768
    float* bew   = (float*)(ws + 13172736);                 // 32,768
    float* uvw   = (float*)(ws + 13205504);                 // 65,536  (end 13,271,040)

    k_prepX<<<16384, 256, 0, stream>>>(X, XBhi);
    k_prepW<<<512, 256, 0, stream>>>(W1, WBhi, WBlo);
    k_h1<<<512, 256, 0, stream>>>(XBhi, WBhi, WBlo, b1, avec, H1TB, alw, bew, uvw);
    hipMemsetAsync(Zw, 0, 32768 + 8388608, stream);         // overwrites XBhi (done)
    k_attn<<<2048, 256, 0, stream>>>(A, H1TB, alw, bew, uvw, H2acc, Zw);
    k_out<<<256, 256, 0, stream>>>(H2acc, Zw, Omega, beta, out);
}